// Round 1
// baseline (15.390 us; speedup 1.0000x reference)
//
#include <hip/hip_runtime.h>

// SLSTMNET: key observation — spk2 = spike(sigmoid(o)*tanh(syn) - 1.0) is
// identically zero (product of sigmoid and tanh is <= 1.0 in fp32, spike
// needs strict > 0). So fc_out == fc_b for every step/batch, and the output
// reduces to a batch-independent 3-channel scalar recursion:
//   reset_t = (m_{t-1} - thr > 0)
//   m_t     = (beta*m_{t-1} + fc_b[j]) - reset_t*thr     (unfused fp32 ops)
//   spk_t   = (m_t - thr > 0)
// Outputs: spk_rec[100,4096,3] then mem_rec[100,4096,3] — a broadcast of a
// 600-entry table. __f*_rn intrinsics prevent -ffp-contract=fast from fusing
// beta*m+b into an FMA (must match XLA's unfused elementwise semantics so the
// binary threshold crossings are bit-identical).

#define R_STEPS   100
#define BATCH     4096
#define OUTC      3
#define HALF_FLOATS (R_STEPS * BATCH * OUTC)   // 1228800
#define PER_T       (BATCH * OUTC)             // 12288

__global__ __launch_bounds__(256) void slstmnet_kernel(
    const float* __restrict__ fc_b,
    const float* __restrict__ beta_p,
    const float* __restrict__ thr_lif_p,
    float4* __restrict__ out,
    int n4)
{
    __shared__ float s_tab[2 * R_STEPS * OUTC];  // [0..299]=spk, [300..599]=mem

    if (threadIdx.x < OUTC) {
        const int   j  = threadIdx.x;
        const float b  = fc_b[j];
        const float be = beta_p[0];
        const float th = thr_lif_p[0];
        float m = 0.0f;
        for (int t = 0; t < R_STEPS; ++t) {
            // reset = spike(mem_prev - thr)
            const float d0    = __fsub_rn(m, th);
            const float reset = (d0 > 0.0f) ? 1.0f : 0.0f;
            // mem = ((beta*mem) + fc_b) - (reset*thr), each op separately rounded
            const float t1 = __fmul_rn(be, m);
            const float t2 = __fadd_rn(t1, b);
            const float t3 = __fmul_rn(reset, th);
            m = __fsub_rn(t2, t3);
            // spk = spike(mem - thr)
            const float d1 = __fsub_rn(m, th);
            s_tab[t * OUTC + j]                   = (d1 > 0.0f) ? 1.0f : 0.0f;
            s_tab[R_STEPS * OUTC + t * OUTC + j]  = m;
        }
    }
    __syncthreads();

    int idx = blockIdx.x * blockDim.x + threadIdx.x;
    const int stride = gridDim.x * blockDim.x;
    for (; idx < n4; idx += stride) {
        const int base = idx * 4;
        float vals[4];
        #pragma unroll
        for (int k = 0; k < 4; ++k) {
            const int f    = base + k;
            const int half = (f >= HALF_FLOATS) ? 1 : 0;
            const int rem  = f - half * HALF_FLOATS;
            const int t    = rem / PER_T;         // compiles to mul_hi magic
            const int j    = rem % OUTC;
            vals[k] = s_tab[half * (R_STEPS * OUTC) + t * OUTC + j];
        }
        float4 v;
        v.x = vals[0]; v.y = vals[1]; v.z = vals[2]; v.w = vals[3];
        out[idx] = v;
    }
}

extern "C" void kernel_launch(void* const* d_in, const int* in_sizes, int n_in,
                              void* d_out, int out_size, void* d_ws, size_t ws_size,
                              hipStream_t stream) {
    // input order: x, W_ih, W_hh, b_ih, b_hh, thr_slstm, fc_w, fc_b, beta, thr_lif
    const float* fc_b    = (const float*)d_in[7];
    const float* beta    = (const float*)d_in[8];
    const float* thr_lif = (const float*)d_in[9];

    const int n4 = out_size / 4;               // 614400 float4 stores
    const int threads = 256;
    const int blocks  = (n4 + threads - 1) / threads;  // 2400

    slstmnet_kernel<<<blocks, threads, 0, stream>>>(
        fc_b, beta, thr_lif, (float4*)d_out, n4);
}

// Round 2
// 12.828 us; speedup vs baseline: 1.1997x; 1.1997x over previous
//
#include <hip/hip_runtime.h>

// SLSTMNET: spk2 = spike(sigmoid(o)*tanh(syn) - 1.0) is identically zero
// (sigmoid*tanh <= 1.0 in fp32; spike needs strict > 0), so fc_out == fc_b and
// the outputs reduce to a batch-independent 3-channel scalar recursion:
//   reset_t = (m_{t-1} - thr > 0)
//   m_t     = (beta*m_{t-1} + fc_b[j]) - reset_t*thr   (unfused fp32, __f*_rn)
//   spk_t   = (m_t - thr > 0)
// Output layout: [half(2)][t(100)][b(4096)][j(3)] — each (half,t) "row" of
// 12288 floats is 4096 repeats of (v0,v1,v2), i.e. 3 distinct float4 patterns:
//   pattern p (= float4_index % 3): (v_p, v_{p+1}, v_{p+2}, v_p)  (mod 3)
// Plan: 3 lanes run the recursion into LDS; build 200 rows x 3 pattern-float4s
// in LDS; then 800 blocks x 256 threads (single resident generation, 1024
// threads per row) each issue 3 coalesced float4 stores with row = tid>>10 —
// no division in the hot path.

#define R_STEPS 100
#define OUTC    3
#define ROWS    (2 * R_STEPS)      // 200
#define F4_PER_ROW 3072            // 12288 floats / 4
#define THREADS_PER_ROW 1024       // 3072 / 3 stores per thread

__global__ __launch_bounds__(256, 4) void slstmnet_kernel(
    const float* __restrict__ fc_b,
    const float* __restrict__ beta_p,
    const float* __restrict__ thr_lif_p,
    float4* __restrict__ out)
{
    __shared__ float  s_val[ROWS * OUTC];   // [r*3+j]: r<100 spk(t=r), r>=100 mem(t=r-100)
    __shared__ float4 s_pat[ROWS * OUTC];   // [r*3+p]: pattern p of row r

    if (threadIdx.x < OUTC) {
        const int   j  = threadIdx.x;
        const float b  = fc_b[j];
        const float be = beta_p[0];
        const float th = thr_lif_p[0];
        float m = 0.0f;
        for (int t = 0; t < R_STEPS; ++t) {
            const float d0    = __fsub_rn(m, th);
            const float reset = (d0 > 0.0f) ? 1.0f : 0.0f;
            const float t1 = __fmul_rn(be, m);
            const float t2 = __fadd_rn(t1, b);
            const float t3 = __fmul_rn(reset, th);
            m = __fsub_rn(t2, t3);
            const float d1 = __fsub_rn(m, th);
            s_val[t * OUTC + j]             = (d1 > 0.0f) ? 1.0f : 0.0f;
            s_val[(R_STEPS + t) * OUTC + j] = m;
        }
    }
    __syncthreads();

    // Build 600 pattern float4s: s_pat[r*3+p] = (v_p, v_{p+1}, v_{p+2}, v_p)
    for (int i = threadIdx.x; i < ROWS * OUTC; i += blockDim.x) {
        const int r  = i / 3;
        const int p  = i - r * 3;
        const int p1 = (p + 1 == 3) ? 0 : p + 1;
        const int p2 = (p1 + 1 == 3) ? 0 : p1 + 1;
        const float v0 = s_val[r * 3 + p];
        const float v1 = s_val[r * 3 + p1];
        const float v2 = s_val[r * 3 + p2];
        float4 f; f.x = v0; f.y = v1; f.z = v2; f.w = v0;
        s_pat[i] = f;
    }
    __syncthreads();

    // Broadcast: thread tg handles row = tg>>10, lane-in-row l = tg & 1023,
    // stores float4s at row*3072 + {l, l+1024, l+2048} with patterns
    // {l%3, (l+1)%3, (l+2)%3}  (1024 % 3 == 1).
    const int tg  = blockIdx.x * blockDim.x + threadIdx.x;   // 0..204799
    const int row = tg >> 10;
    const int l   = tg & 1023;
    const int lp  = l % 3;

    const float4 p0 = s_pat[row * 3 + 0];
    const float4 p1 = s_pat[row * 3 + 1];
    const float4 p2 = s_pat[row * 3 + 2];

    const float4 a = (lp == 0) ? p0 : ((lp == 1) ? p1 : p2);  // pattern l%3
    const float4 b = (lp == 0) ? p1 : ((lp == 1) ? p2 : p0);  // pattern (l+1)%3
    const float4 c = (lp == 0) ? p2 : ((lp == 1) ? p0 : p1);  // pattern (l+2)%3

    float4* rowp = out + (size_t)row * F4_PER_ROW;
    rowp[l]        = a;
    rowp[l + 1024] = b;
    rowp[l + 2048] = c;
}

extern "C" void kernel_launch(void* const* d_in, const int* in_sizes, int n_in,
                              void* d_out, int out_size, void* d_ws, size_t ws_size,
                              hipStream_t stream) {
    // input order: x, W_ih, W_hh, b_ih, b_hh, thr_slstm, fc_w, fc_b, beta, thr_lif
    const float* fc_b    = (const float*)d_in[7];
    const float* beta    = (const float*)d_in[8];
    const float* thr_lif = (const float*)d_in[9];

    // 200 rows * 1024 threads/row = 204800 threads = 800 blocks of 256.
    // All blocks resident in one generation (<= 2048 block capacity).
    slstmnet_kernel<<<800, 256, 0, stream>>>(fc_b, beta, thr_lif, (float4*)d_out);
}

// Round 3
// 10.969 us; speedup vs baseline: 1.4030x; 1.1695x over previous
//
#include <hip/hip_runtime.h>

// SLSTMNET: spk2 = spike(sigmoid(o)*tanh(syn) - 1.0) is identically zero
// (sigmoid*tanh <= 1.0 in fp32; spike needs strict > 0), so fc_out == fc_b and
// the outputs reduce to a batch-independent 3-channel scalar recursion:
//   m_t   = (beta*m_{t-1} + fc_b[j]) - ((m_{t-1}-thr > 0) ? thr : 0)
//   spk_t = (m_t - thr > 0)
// (t3=(d0>0)?thr:0 is bit-identical to reset*thr since 1.0*thr==thr, 0*thr==0;
//  __f*_rn keeps ops unfused to match XLA's elementwise rounding at the
//  binary threshold crossings.)
//
// Output [half(2)][t(100)][b(4096)][j(3)]: each (half,t) row of 12288 floats
// is 4096 repeats of (v0,v1,v2) -> 3 distinct float4 patterns per row.
// Grid: 800 blocks x 256. row = blockIdx.x>>2 is UNIFORM per block, so each
// block runs the recursion only up to its own t_need = row%100 (3 lanes),
// writes 3 floats to LDS, then all threads broadcast-read and issue 3
// coalesced float4 stores. Early rows start storing immediately, overlapping
// store BW with late rows' serial compute; critical path = 100 steps x 4
// dependent VALU ops ~= 0.7 us, store floor ~= 1.4 us, rest is launch overhead.

#define R_STEPS 100
#define F4_PER_ROW 3072   // 12288 floats / 4

__global__ __launch_bounds__(256) void slstmnet_kernel(
    const float* __restrict__ fc_b,
    const float* __restrict__ beta_p,
    const float* __restrict__ thr_lif_p,
    float4* __restrict__ out)
{
    __shared__ float s_v[4];

    const int row = blockIdx.x >> 2;          // 0..199, uniform per block

    if (threadIdx.x < 3) {
        const int   j  = threadIdx.x;
        const float b  = fc_b[j];
        const float be = beta_p[0];
        const float th = thr_lif_p[0];
        const int t_need = (row < R_STEPS) ? row : (row - R_STEPS);
        float m = 0.0f;
        for (int t = 0; t <= t_need; ++t) {
            const float d0 = __fsub_rn(m, th);
            const float t3 = (d0 > 0.0f) ? th : 0.0f;   // == reset*thr exactly
            const float t1 = __fmul_rn(be, m);
            const float t2 = __fadd_rn(t1, b);
            m = __fsub_rn(t2, t3);
        }
        const float d1  = __fsub_rn(m, th);
        const float spk = (d1 > 0.0f) ? 1.0f : 0.0f;
        s_v[j] = (row < R_STEPS) ? spk : m;
    }
    __syncthreads();

    const float v0 = s_v[0], v1 = s_v[1], v2 = s_v[2];

    // float4 index f4 within row has pattern p = f4 % 3:
    //   p0=(v0,v1,v2,v0)  p1=(v1,v2,v0,v1)  p2=(v2,v0,v1,v2)
    float4 p0; p0.x = v0; p0.y = v1; p0.z = v2; p0.w = v0;
    float4 p1; p1.x = v1; p1.y = v2; p1.z = v0; p1.w = v1;
    float4 p2; p2.x = v2; p2.y = v0; p2.z = v1; p2.w = v2;

    const int l  = ((blockIdx.x & 3) << 8) + threadIdx.x;  // 0..1023 in row
    const int lp = l % 3;

    // stores at f4 = l, l+1024, l+2048; 1024 % 3 == 1 so patterns rotate
    const float4 a = (lp == 0) ? p0 : ((lp == 1) ? p1 : p2);
    const float4 b = (lp == 0) ? p1 : ((lp == 1) ? p2 : p0);
    const float4 c = (lp == 0) ? p2 : ((lp == 1) ? p0 : p1);

    float4* rowp = out + (size_t)row * F4_PER_ROW;
    rowp[l]        = a;
    rowp[l + 1024] = b;
    rowp[l + 2048] = c;
}

extern "C" void kernel_launch(void* const* d_in, const int* in_sizes, int n_in,
                              void* d_out, int out_size, void* d_ws, size_t ws_size,
                              hipStream_t stream) {
    // input order: x, W_ih, W_hh, b_ih, b_hh, thr_slstm, fc_w, fc_b, beta, thr_lif
    const float* fc_b    = (const float*)d_in[7];
    const float* beta    = (const float*)d_in[8];
    const float* thr_lif = (const float*)d_in[9];

    // 200 rows x 4 blocks/row = 800 blocks, single resident generation.
    slstmnet_kernel<<<800, 256, 0, stream>>>(fc_b, beta, thr_lif, (float4*)d_out);
}

// Round 4
// 10.577 us; speedup vs baseline: 1.4550x; 1.0370x over previous
//
#include <hip/hip_runtime.h>

// SLSTMNET: spk2 = spike(sigmoid(o)*tanh(syn) - 1.0) is identically zero
// (sigmoid*tanh <= 1.0 in fp32; spike needs strict > 0), so fc_out == fc_b and
// the outputs reduce to a batch-independent 3-channel scalar recursion:
//   m_t   = (beta*m_{t-1} + fc_b[j]) - ((m_{t-1}-thr > 0) ? thr : 0)
//   spk_t = (m_t - thr > 0)
// ((d0>0)?thr:0 is bit-identical to reset*thr: 1.0*thr==thr, 0.0*thr==0.0;
//  __f*_rn keeps ops unfused to match XLA's elementwise rounding at the
//  binary threshold crossings.)
//
// Output [half(2)][t(100)][b(4096)][j(3)]: each (half,t) row of 12288 floats
// is 4096 repeats of (v0,v1,v2) -> 3 distinct float4 store patterns.
//
// R4 changes vs R3 (10.97 us):
//  - REVERSED row mapping: longest recursion chains (t=99) get the lowest
//    blockIdx so they dispatch/start first; trivial rows (t~0) dispatch last
//    and only store -> removes the serial chain from the kernel's tail.
//  - No barrier/LDS: all 64 lanes of each wave run the (uniform-trip) loop
//    redundantly with channel min(lane,2); 3 __shfl broadcasts replace
//    __syncthreads + LDS round-trip, so each wave stores the moment its own
//    chain finishes.

#define R_STEPS 100
#define ROWS    200
#define F4_PER_ROW 3072   // 12288 floats / 4

__global__ __launch_bounds__(256) void slstmnet_kernel(
    const float* __restrict__ fc_b,
    const float* __restrict__ beta_p,
    const float* __restrict__ thr_lif_p,
    float4* __restrict__ out)
{
    // Reverse: blockIdx 0..3 -> row 199 (t=99 mem half), last blocks -> row 0.
    const int row = (ROWS - 1) - (int)(blockIdx.x >> 2);   // uniform per block

    const int lane = threadIdx.x & 63;
    const int ch   = (lane < 3) ? lane : 2;

    const float b  = fc_b[ch];
    const float be = beta_p[0];
    const float th = thr_lif_p[0];

    const int t_need = (row < R_STEPS) ? row : (row - R_STEPS);
    float m = 0.0f;
    for (int t = 0; t <= t_need; ++t) {
        const float d0 = __fsub_rn(m, th);
        const float t3 = (d0 > 0.0f) ? th : 0.0f;   // == reset*thr exactly
        const float t1 = __fmul_rn(be, m);
        const float t2 = __fadd_rn(t1, b);
        m = __fsub_rn(t2, t3);
    }
    const float d1  = __fsub_rn(m, th);
    const float spk = (d1 > 0.0f) ? 1.0f : 0.0f;
    const float val = (row < R_STEPS) ? spk : m;

    const float v0 = __shfl(val, 0);
    const float v1 = __shfl(val, 1);
    const float v2 = __shfl(val, 2);

    // float4 index f4 within row has pattern p = f4 % 3:
    //   p0=(v0,v1,v2,v0)  p1=(v1,v2,v0,v1)  p2=(v2,v0,v1,v2)
    float4 p0; p0.x = v0; p0.y = v1; p0.z = v2; p0.w = v0;
    float4 p1; p1.x = v1; p1.y = v2; p1.z = v0; p1.w = v1;
    float4 p2; p2.x = v2; p2.y = v0; p2.z = v1; p2.w = v2;

    const int l  = ((blockIdx.x & 3) << 8) + threadIdx.x;  // 0..1023 in row
    const int lp = l % 3;

    // stores at f4 = l, l+1024, l+2048; 1024 % 3 == 1 so patterns rotate
    const float4 a = (lp == 0) ? p0 : ((lp == 1) ? p1 : p2);
    const float4 bq = (lp == 0) ? p1 : ((lp == 1) ? p2 : p0);
    const float4 c = (lp == 0) ? p2 : ((lp == 1) ? p0 : p1);

    float4* rowp = out + (size_t)row * F4_PER_ROW;
    rowp[l]        = a;
    rowp[l + 1024] = bq;
    rowp[l + 2048] = c;
}

extern "C" void kernel_launch(void* const* d_in, const int* in_sizes, int n_in,
                              void* d_out, int out_size, void* d_ws, size_t ws_size,
                              hipStream_t stream) {
    // input order: x, W_ih, W_hh, b_ih, b_hh, thr_slstm, fc_w, fc_b, beta, thr_lif
    const float* fc_b    = (const float*)d_in[7];
    const float* beta    = (const float*)d_in[8];
    const float* thr_lif = (const float*)d_in[9];

    // 200 rows x 4 blocks/row = 800 blocks, single resident generation.
    slstmnet_kernel<<<800, 256, 0, stream>>>(fc_b, beta, thr_lif, (float4*)d_out);
}